// Round 10
// baseline (323.336 us; speedup 1.0000x reference)
//
#include <hip/hip_runtime.h>

typedef float4 f4;

// ---- ws float-offset layout ----
#define F_S0    0        // 64: per-channel W0 scale
#define F_BN0   64       // g[64] be[64] m[64] r[64]
#define F_BN1   320
#define F_BN2   576
#define F_BN3   832      // 256 floats (c<10 valid, rest 0)
#define F_WQ1   1088     // [16][64][4] fp32
#define F_WQ2   5184     // [16][64][4]
#define F_WQ3   9280     // [16][64][4] (zeros for c>=10)
#define F_WI0   13376    // int8 W0 tiled [768][64][4] = 196608 B
#define F_WQ0   62528    // fp32 W0 tiled [768][64][4] = 196608 floats
#define WS_NEED_F32 ((size_t)(F_WQ0 + 196608) * 4)

struct InPtrs { const float* p[25]; };

// ---------------- prep: fp32 scales/weights/BN consts (np-f32 exact ops) ----------------
__global__ __launch_bounds__(256) void qtfc_prep(InPtrs P, float* __restrict__ wsf, int wf32) {
#pragma clang fp contract(off)
  __shared__ float red[256];
  const int tid = threadIdx.x, b = blockIdx.x;
  if (b < 64) {
    const int c = b;                       // output channel
    const float* W = P.p[1];
    float mx = 0.f;
    for (int k = tid; k < 3072; k += 256) mx = fmaxf(mx, fabsf(W[c * 3072 + k]));
    red[tid] = mx; __syncthreads();
    for (int s = 128; s > 0; s >>= 1) { if (tid < s) red[tid] = fmaxf(red[tid], red[tid + s]); __syncthreads(); }
    const float sv = fmaxf(__fdiv_rn(red[0], 7.f), 1e-8f);
    signed char* wi = (signed char*)(wsf + F_WI0);
    for (int k = tid; k < 3072; k += 256) {
      const float r = rintf(__fdiv_rn(W[c * 3072 + k], sv));
      const int idx = (k >> 2) * 256 + c * 4 + (k & 3);   // [chunk][lane=c][4]
      wi[idx] = (signed char)(int)r;
      if (wf32) wsf[F_WQ0 + idx] = __fmul_rn(r, sv);
    }
    if (tid == 0) {
      wsf[F_S0 + c] = sv;
      const float gg = P.p[3][c], be = P.p[4][c], m = P.p[5][c], v = P.p[6][c];
      const float rr = __fdiv_rn(1.f, __fsqrt_rn(__fadd_rn(v, 1e-5f)));
      wsf[F_BN0 + c] = gg; wsf[F_BN0 + 64 + c] = be; wsf[F_BN0 + 128 + c] = m; wsf[F_BN0 + 192 + c] = rr;
    }
  } else if (b < 192) {
    const int lay = b >> 6, c = b & 63;    // lay = 1,2
    const float* W = P.p[1 + 6 * lay];
    red[tid] = (tid < 64) ? fabsf(W[c * 64 + tid]) : 0.f; __syncthreads();
    for (int s = 128; s > 0; s >>= 1) { if (tid < s) red[tid] = fmaxf(red[tid], red[tid + s]); __syncthreads(); }
    const float sv = fmaxf(__fdiv_rn(red[0], 7.f), 1e-8f);
    float* wq = wsf + (lay == 1 ? F_WQ1 : F_WQ2);
    if (tid < 64) {
      const int k = tid;
      wq[(k >> 2) * 256 + c * 4 + (k & 3)] = __fmul_rn(rintf(__fdiv_rn(W[c * 64 + k], sv)), sv);
    }
    if (tid == 0) {
      const int base = (lay == 1) ? F_BN1 : F_BN2;
      const float gg = P.p[3 + 6 * lay][c], be = P.p[4 + 6 * lay][c];
      const float m = P.p[5 + 6 * lay][c], v = P.p[6 + 6 * lay][c];
      const float rr = __fdiv_rn(1.f, __fsqrt_rn(__fadd_rn(v, 1e-5f)));
      wsf[base + c] = gg; wsf[base + 64 + c] = be; wsf[base + 128 + c] = m; wsf[base + 192 + c] = rr;
    }
  } else {
    // W3: zero-pad then per-tensor quant over 10x64
    for (int i = tid; i < 4096; i += 256) wsf[F_WQ3 + i] = 0.f;
    for (int i = tid; i < 256; i += 256) wsf[F_BN3 + i] = 0.f;
    __syncthreads();
    const float* W = P.p[19];
    float mx = 0.f;
    for (int k = tid; k < 640; k += 256) mx = fmaxf(mx, fabsf(W[k]));
    red[tid] = mx; __syncthreads();
    for (int s = 128; s > 0; s >>= 1) { if (tid < s) red[tid] = fmaxf(red[tid], red[tid + s]); __syncthreads(); }
    const float sv = fmaxf(__fdiv_rn(red[0], 7.f), 1e-8f);
    for (int i = tid; i < 640; i += 256) {
      const int c = i >> 6, k = i & 63;
      wsf[F_WQ3 + (k >> 2) * 256 + c * 4 + (k & 3)] = __fmul_rn(rintf(__fdiv_rn(W[i], sv)), sv);
    }
    if (tid < 10) {
      const float gg = P.p[21][tid], be = P.p[22][tid], m = P.p[23][tid], v = P.p[24][tid];
      const float rr = __fdiv_rn(1.f, __fsqrt_rn(__fadd_rn(v, 1e-5f)));
      wsf[F_BN3 + tid] = gg; wsf[F_BN3 + 16 + tid] = be; wsf[F_BN3 + 32 + tid] = m; wsf[F_BN3 + 48 + tid] = rr;
    }
  }
}

// ---------------- exact-np helpers ----------------
__device__ __forceinline__ float bn_act4(float hv, float g, float be, float m, float r) {
#pragma clang fp contract(off)
  const float bnv = __fadd_rn(__fmul_rn(__fmul_rn(g, __fsub_rn(hv, m)), r), be);
  const float y = fminf(fmaxf(bnv, -1.f), 1.f);
  return __fdiv_rn(rintf(__fmul_rn(y, 7.f)), 7.f);
}
__device__ __forceinline__ float lutq(float v, const float* lut) {
#pragma clang fp contract(off)
  const float y = fminf(fmaxf(v, -1.f), 1.f);
  const float r = rintf(__fmul_rn(y, 127.f));
  return lut[(int)r + 127];   // == __fdiv_rn(r, 127.f)
}
__device__ __forceinline__ f4 q4(f4 v, const float* lut) {
  f4 q; q.x = lutq(v.x, lut); q.y = lutq(v.y, lut); q.z = lutq(v.z, lut); q.w = lutq(v.w, lut);
  return q;
}
__device__ __forceinline__ void decw(int d, float sv, f4* dst) {
#pragma clang fp contract(off)
  f4 o;
  o.x = __fmul_rn((float)((signed char)(d & 255)), sv);
  o.y = __fmul_rn((float)((signed char)((d >> 8) & 255)), sv);
  o.z = __fmul_rn((float)((signed char)((d >> 16) & 255)), sv);
  o.w = __fmul_rn((float)((signed char)((d >> 24) & 255)), sv);
  *dst = o;
}

// ---- main: 8 rows/wave, lane = (row-half rh, ch-pair c/c+32); padded LDS (no addr VALU) ----
template<int W8>
__global__ __launch_bounds__(256) void qtfc_main(const float* __restrict__ x,
                                                 const float* __restrict__ wsf,
                                                 float* __restrict__ out) {
#pragma clang fp contract(off)
  // [0:4352) x-tiles: 4 waves x (2 bufs x 8 rows x 17 f4); [4352:4608) lut; [4608:8704) W8 weight tile
  __shared__ __align__(16) float smem[8704];
  const int tid = threadIdx.x, w = tid >> 6, l = tid & 63;
  float* R = smem + w * 1088;
  f4* xt4 = (f4*)R;
  float* lut = smem + 4352;
  f4* wt4 = (f4*)(smem + 4608);        // [16 cc][64 ch] f4
  const int row0w = blockIdx.x * 32 + w * 8;

  if (tid < 255) lut[tid] = __fdiv_rn((float)(tid - 127), 127.f);

  const int c_lo = l & 31, rh = l >> 5;
  const int rowl = l >> 3, sb = l & 7;
  const float* xb = x + (long)(row0w + rowl) * 3072 + sb * 4;
  f4* xs0 = xt4 + rowl * 17 + sb;          // stage base, buffer0 (write [0] and [8])
  f4* xs1 = xs0 + 136;                     // buffer1
  const f4* xr0 = xt4 + rh * 68;           // read base, buffer0 (read [r4*17+c])
  const f4* xr1 = xr0 + 136;

  const f4* wq0 = (const f4*)(wsf + F_WQ0);
  const int4* wi4 = (const int4*)(wsf + F_WI0);   // 256 int4 per 64-k tile
  const int dcc = tid >> 4, dc0 = (tid & 15) * 4; // decode: thread -> (cc, 4 channels)
  f4 sv4 = {0.f, 0.f, 0.f, 0.f};
  if (W8) sv4 = *(const f4*)(wsf + F_S0 + dc0);
  f4* wdst = wt4 + dcc * 64 + dc0;
  const f4* wlb = wt4 + c_lo;              // consume base (offset-immediate reads)

  float accL[4], accH[4], hsL[4], hsH[4];
#pragma unroll
  for (int r = 0; r < 4; ++r) { accL[r] = 0.f; accH[r] = 0.f; hsL[r] = 0.f; hsH[r] = 0.f; }

  // prologue
  f4 gx0 = *(const f4*)(xb);
  f4 gx1 = *(const f4*)(xb + 32);
  int4 gwi = {0, 0, 0, 0};
  if (W8) gwi = wi4[tid];
  __syncthreads();                         // lut visible
  xs0[0] = q4(gx0, lut);
  xs0[8] = q4(gx1, lut);
  if (W8) {
    decw(gwi.x, sv4.x, wdst + 0);
    decw(gwi.y, sv4.y, wdst + 1);
    decw(gwi.z, sv4.z, wdst + 2);
    decw(gwi.w, sv4.w, wdst + 3);
    gwi = wi4[256 + tid];                  // tile 1
  }
  gx0 = *(const f4*)(xb + 64);
  gx1 = *(const f4*)(xb + 96);
  __syncthreads();                         // wtile0 visible (harmless for wf32)

  f4 wAL[2], wAH[2], wBL[2], wBH[2];

#define LDWF(WL, WH, G0)                                           \
  { _Pragma("unroll")                                              \
    for (int cc2 = 0; cc2 < 2; ++cc2) {                            \
      WL[cc2] = wq0[((G0) + cc2) * 64 + c_lo];                     \
      WH[cc2] = wq0[((G0) + cc2) * 64 + c_lo + 32];                \
    } }

#define FMA8(wl, wh, xv)                                           \
  { float aL = accL[r4], aH = accH[r4];                            \
    aL = __fmaf_rn(xv.x, wl.x, aL); aH = __fmaf_rn(xv.x, wh.x, aH);\
    aL = __fmaf_rn(xv.y, wl.y, aL); aH = __fmaf_rn(xv.y, wh.y, aH);\
    aL = __fmaf_rn(xv.z, wl.z, aL); aH = __fmaf_rn(xv.z, wh.z, aH);\
    aL = __fmaf_rn(xv.w, wl.w, aL); aH = __fmaf_rn(xv.w, wh.w, aH);\
    accL[r4] = aL; accH[r4] = aH; }

#define FMAGF(WL, WH, C0, XR)                                      \
  { _Pragma("unroll")                                              \
    for (int cc2 = 0; cc2 < 2; ++cc2) {                            \
      const f4 wl = WL[cc2], wh = WH[cc2];                         \
      _Pragma("unroll")                                            \
      for (int r4 = 0; r4 < 4; ++r4) {                             \
        const f4 xv = (XR)[r4 * 17 + (C0) + cc2];                  \
        FMA8(wl, wh, xv)                                           \
      } } }

#define FMAGW(C0, XR)                                              \
  { _Pragma("unroll")                                              \
    for (int cc2 = 0; cc2 < 2; ++cc2) {                            \
      const int _c = (C0) + cc2;                                   \
      const f4 wl = wlb[_c * 64];                                  \
      const f4 wh = wlb[_c * 64 + 32];                             \
      _Pragma("unroll")                                            \
      for (int r4 = 0; r4 < 4; ++r4) {                             \
        const f4 xv = (XR)[r4 * 17 + _c];                          \
        FMA8(wl, wh, xv)                                           \
      } } }

  if (!W8) LDWF(wAL, wAH, 0);

#pragma unroll 1
  for (int t = 0; t < 48; ++t) {
    const f4* xw = (t & 1) ? xr1 : xr0;
    f4* xsn = (t & 1) ? xs0 : xs1;
    const int tn = (t + 2 < 48) ? t + 2 : 47;

    if (!W8) {
      const int g0 = t * 16;
      LDWF(wBL, wBH, g0 + 2);  FMAGF(wAL, wAH, 0, xw);
      LDWF(wAL, wAH, g0 + 4);  FMAGF(wBL, wBH, 2, xw);
      LDWF(wBL, wBH, g0 + 6);
      if (t < 47) { xsn[0] = q4(gx0, lut); xsn[8] = q4(gx1, lut); }
      FMAGF(wAL, wAH, 4, xw);
      LDWF(wAL, wAH, g0 + 8);  FMAGF(wBL, wBH, 6, xw);
      LDWF(wBL, wBH, g0 + 10);
      gx0 = *(const f4*)(xb + tn * 64);
      gx1 = *(const f4*)(xb + tn * 64 + 32);
      FMAGF(wAL, wAH, 8, xw);
      LDWF(wAL, wAH, g0 + 12); FMAGF(wBL, wBH, 10, xw);
      LDWF(wBL, wBH, g0 + 14); FMAGF(wAL, wAH, 12, xw);
      LDWF(wAL, wAH, (t < 47) ? (g0 + 16) : (g0 + 14));
      FMAGF(wBL, wBH, 14, xw);
    } else {
      FMAGW(0, xw);  FMAGW(2, xw);
      if (t < 47) { xsn[0] = q4(gx0, lut); xsn[8] = q4(gx1, lut); }
      FMAGW(4, xw);  FMAGW(6, xw);
      gx0 = *(const f4*)(xb + tn * 64);
      gx1 = *(const f4*)(xb + tn * 64 + 32);
      FMAGW(8, xw);  FMAGW(10, xw); FMAGW(12, xw); FMAGW(14, xw);
    }

    if ((t % 6) == 5) {     // KC=384 boundary: sequential fp32 block-sum combine
#pragma unroll
      for (int r = 0; r < 4; ++r) {
        hsL[r] = __fadd_rn(hsL[r], accL[r]); accL[r] = 0.f;
        hsH[r] = __fadd_rn(hsH[r], accH[r]); accH[r] = 0.f;
      }
    }

    if (W8) {
      __syncthreads();                     // all waves done reading wtile
      if (t < 47) {
        decw(gwi.x, sv4.x, wdst + 0);
        decw(gwi.y, sv4.y, wdst + 1);
        decw(gwi.z, sv4.z, wdst + 2);
        decw(gwi.w, sv4.w, wdst + 3);
        gwi = wi4[tn * 256 + tid];         // tile t+2
      }
      __syncthreads();                     // wtile(t+1) ready
    }
  }
#undef LDWF
#undef FMAGF
#undef FMAGW
#undef FMA8

  float* xa1 = R;            // a1 [8][64] floats
  float* a2  = R + 512;

  // ---- layer-0 epilogue: BN + 4-bit act -> a1 ----
  {
    const float gL = wsf[F_BN0 + c_lo],       beL = wsf[F_BN0 + 64 + c_lo];
    const float mL = wsf[F_BN0 + 128 + c_lo], rL  = wsf[F_BN0 + 192 + c_lo];
    const float gH = wsf[F_BN0 + 32 + c_lo],  beH = wsf[F_BN0 + 96 + c_lo];
    const float mH = wsf[F_BN0 + 160 + c_lo], rH  = wsf[F_BN0 + 224 + c_lo];
#pragma unroll
    for (int r4 = 0; r4 < 4; ++r4) {
      const int rr = rh * 4 + r4;
      xa1[rr * 64 + c_lo]      = bn_act4(hsL[r4], gL, beL, mL, rL);
      xa1[rr * 64 + c_lo + 32] = bn_act4(hsH[r4], gH, beH, mH, rH);
    }
  }

  // ---- layer 1: a1 -> a2 (lane = channel l, 8 rows) ----
  {
    const f4* wq1 = (const f4*)(wsf + F_WQ1);
    const f4* a14 = (const f4*)xa1;
    float a1c[8];
#pragma unroll
    for (int r = 0; r < 8; ++r) a1c[r] = 0.f;
#pragma unroll
    for (int cc = 0; cc < 16; ++cc) {
      const f4 wf = wq1[cc * 64 + l];
#pragma unroll
      for (int r = 0; r < 8; ++r) {
        const f4 xv = a14[r * 16 + cc];
        float a = a1c[r];
        a = __fmaf_rn(xv.x, wf.x, a);
        a = __fmaf_rn(xv.y, wf.y, a);
        a = __fmaf_rn(xv.z, wf.z, a);
        a = __fmaf_rn(xv.w, wf.w, a);
        a1c[r] = a;
      }
    }
    const float g = wsf[F_BN1 + l], be = wsf[F_BN1 + 64 + l];
    const float m = wsf[F_BN1 + 128 + l], rr = wsf[F_BN1 + 192 + l];
#pragma unroll
    for (int r = 0; r < 8; ++r)
      a2[r * 64 + l] = bn_act4(a1c[r], g, be, m, rr);
  }

  // ---- layer 2: a2 -> a1 ----
  {
    const f4* wq2 = (const f4*)(wsf + F_WQ2);
    const f4* a24 = (const f4*)a2;
    float a2c[8];
#pragma unroll
    for (int r = 0; r < 8; ++r) a2c[r] = 0.f;
#pragma unroll
    for (int cc = 0; cc < 16; ++cc) {
      const f4 wf = wq2[cc * 64 + l];
#pragma unroll
      for (int r = 0; r < 8; ++r) {
        const f4 xv = a24[r * 16 + cc];
        float a = a2c[r];
        a = __fmaf_rn(xv.x, wf.x, a);
        a = __fmaf_rn(xv.y, wf.y, a);
        a = __fmaf_rn(xv.z, wf.z, a);
        a = __fmaf_rn(xv.w, wf.w, a);
        a2c[r] = a;
      }
    }
    const float g = wsf[F_BN2 + l], be = wsf[F_BN2 + 64 + l];
    const float m = wsf[F_BN2 + 128 + l], rr = wsf[F_BN2 + 192 + l];
#pragma unroll
    for (int r = 0; r < 8; ++r)
      xa1[r * 64 + l] = bn_act4(a2c[r], g, be, m, rr);
  }

  // ---- layer 3: 10 outputs, BN affine, no act ----
  {
    const f4* wq3 = (const f4*)(wsf + F_WQ3);
    const f4* a14 = (const f4*)xa1;
    float a3c[8];
#pragma unroll
    for (int r = 0; r < 8; ++r) a3c[r] = 0.f;
#pragma unroll
    for (int cc = 0; cc < 16; ++cc) {
      const f4 wf = wq3[cc * 64 + l];
#pragma unroll
      for (int r = 0; r < 8; ++r) {
        const f4 xv = a14[r * 16 + cc];
        float a = a3c[r];
        a = __fmaf_rn(xv.x, wf.x, a);
        a = __fmaf_rn(xv.y, wf.y, a);
        a = __fmaf_rn(xv.z, wf.z, a);
        a = __fmaf_rn(xv.w, wf.w, a);
        a3c[r] = a;
      }
    }
    if (l < 10) {
      const float g = wsf[F_BN3 + l], be = wsf[F_BN3 + 16 + l];
      const float m = wsf[F_BN3 + 32 + l], rr = wsf[F_BN3 + 48 + l];
#pragma unroll
      for (int r = 0; r < 8; ++r) {
        const float o = __fadd_rn(__fmul_rn(__fmul_rn(g, __fsub_rn(a3c[r], m)), rr), be);
        out[(long)(row0w + r) * 10 + l] = o;
      }
    }
  }
}

extern "C" void kernel_launch(void* const* d_in, const int* in_sizes, int n_in,
                              void* d_out, int out_size, void* d_ws, size_t ws_size,
                              hipStream_t stream) {
  (void)in_sizes; (void)n_in; (void)out_size;
  InPtrs P;
  for (int i = 0; i < 25; ++i) P.p[i] = (const float*)d_in[i];
  float* wsf = (float*)d_ws;
  const int wf32 = (ws_size >= WS_NEED_F32) ? 1 : 0;
  qtfc_prep<<<193, 256, 0, stream>>>(P, wsf, wf32);
  if (wf32)
    qtfc_main<0><<<1024, 256, 0, stream>>>((const float*)d_in[0], wsf, (float*)d_out);
  else
    qtfc_main<1><<<1024, 256, 0, stream>>>((const float*)d_in[0], wsf, (float*)d_out);
}